// Round 7
// baseline (711.729 us; speedup 1.0000x reference)
//
#include <hip/hip_runtime.h>

// GRNN scan: B=512 sequences, T=8192 steps. Round 17.
// R16 post-mortem: fused producer hidden (761->514, fused2=422), but the
// consumer is invariant at ~210-250 cyc/granule across R12/R15/R16 -> the
// cost is IN-WAVE: ~60-70cyc x-chain dependency latency + 32 scalar VALU
// issue, fully exposed at 1 wave/SIMD. External changes can't fix it.
// R17: (a) packed math - GRANC is natural float2 column form (dx = M.x +
// Xi.dy, ov = C.x) -> v_pk_fma_f32 via ext-vectors + elementwise builtins,
// 32 -> ~18 VALU/granule; (b) 2 independent rows per lane (4 blocks x 128
// rows): two x-chains interleave to fill each other's dep bubbles, W-ring
// ds_reads SHARED (amortized 2x). Producer (xi-space) unchanged, hidden.

#define DT_C 1e-3f
#define MAXU 0.1f
#define T_LEN 8192
#define T4 (T_LEN / 2)          // 4096 float4 granules (2 steps each)
#define CHUNK 256               // steps per chunk
#define G_CHUNK (CHUNK / 2)     // 128 granules per chunk
#define NCHUNK (T_LEN / CHUNK)  // 32
#define BROWS 512               // batch rows

typedef float f2 __attribute__((ext_vector_type(2)));
typedef float f4v __attribute__((ext_vector_type(4)));

__device__ __forceinline__ float clipf(float v, float lo, float hi) {
    return fminf(fmaxf(v, lo), hi);
}
__device__ __forceinline__ f2 pkfma(f2 a, f2 b, f2 c) {
    return __builtin_elementwise_fma(a, b, c);
}
__device__ __forceinline__ f2 pkclip(f2 v) {
    const f2 lo = {-MAXU, -MAXU}, hi = {MAXU, MAXU};
    return __builtin_elementwise_min(__builtin_elementwise_max(v, lo), hi);
}
#define SB() __builtin_amdgcn_sched_barrier(0)

// ---------------- tiled float4 transpose: src[rows][cols] -> dst[cols][rows]
__global__ __launch_bounds__(256) void transpose_f4(
    const float4* __restrict__ src, float4* __restrict__ dst,
    int rows, int cols)
{
    __shared__ float4 tile[32][33];
    const int tx = threadIdx.x & 31;
    const int ty = threadIdx.x >> 5;
    const int c0 = blockIdx.x * 32;
    const int r0 = blockIdx.y * 32;
#pragma unroll
    for (int i = 0; i < 32; i += 8)
        tile[ty + i][tx] = src[(size_t)(r0 + ty + i) * cols + (c0 + tx)];
    __syncthreads();
#pragma unroll
    for (int i = 0; i < 32; i += 8)
        dst[(size_t)(c0 + ty + i) * rows + (r0 + tx)] = tile[tx][ty + i];
}

// ============= fused scan: wave0 consumer (2 rows/lane), wave1 producer ===
// inT/outT are [T4][BROWS] float4 (transposed layout, proven R12).
__global__ __launch_bounds__(128, 1) void grnn_fused3(
    const float4* __restrict__ inT, const float* __restrict__ Am,
    const float* __restrict__ Cm, const float* __restrict__ Dm,
    float4* __restrict__ outT)
{
    __shared__ float4 wlds[2][CHUNK * 2];   // 16 KB W double buffer
    __shared__ float4 sbnd[CHUNK / 8];      // 32 sub-boundaries (every 8 steps)
    const int tid = threadIdx.x;
    const int wv = tid >> 6;

    if (wv == 1) {
        // ===================== producer wave (unchanged R16) =============
        const int lane = tid & 63;
        const float a00 = Am[0], a01 = Am[1], a10 = Am[2], a11 = Am[3];
        const float c00 = Cm[0], c01 = Cm[1], c10 = Cm[2], c11 = Cm[3];
        const float d00 = Dm[0], d01 = Dm[1], d10 = Dm[2], d11 = Dm[3];
        const bool special = (c00 == 1.f) && (c01 == 0.f) && (c10 == 0.f) &&
                             (c11 == 1.f) && (d01 == 0.f) && (d10 == 0.f);
        const float adt00 = a00 * DT_C, adt01 = a01 * DT_C;
        const float adt10 = a10 * DT_C, adt11 = a11 * DT_C;

        if (special) {
            // xi-space: u=p00+d00, w=p01, v=p11+d11 (== RSTEP_S algebra)
            const float K00 = 1.f + 2.f * adt00, A2dt01 = 2.f * adt01;
            const float K11 = 1.f + 2.f * adt11, A2dt10 = 2.f * adt10;
            const float K01 = 1.f + (a00 + a11) * DT_C;
            const float C0u = DT_C * d00 * (1.f - 2.f * a00);
            const float C0v = DT_C * d11 * (1.f - 2.f * a11);
            const float C1w = -(adt10 * d00 + adt01 * d11);

#define XSTEP()                                                               \
            {                                                                 \
                const float w2 = w * w;                                       \
                const float gu = fmaf(-DT_C, u, K00);                         \
                const float gv = fmaf(-DT_C, v, K11);                         \
                const float s  = u + v;                                       \
                const float ru = fmaf(A2dt01, w, fmaf(-DT_C, w2, C0u));       \
                const float rv = fmaf(A2dt10, w, fmaf(-DT_C, w2, C0v));       \
                const float gw = fmaf(-DT_C, s, K01);                         \
                const float rw = fmaf(adt10, u, fmaf(adt01, v, C1w));         \
                const float un = fmaf(u, gu, ru);                             \
                const float vn = fmaf(v, gv, rv);                             \
                const float wn = fmaf(w, gw, rw);                             \
                u = un; v = vn; w = wn;                                       \
            }

            float u = 1.f + d00, w = 0.f, v = 1.f + d11;  // P0=I
            for (int it = 0; it <= NCHUNK; ++it) {
                if (it < NCHUNK) {
                    if (lane == 0) {
                        for (int j = 0; j < CHUNK / 8; ++j) {
                            sbnd[j] = make_float4(u, w, v, 0.f);
                            XSTEP() XSTEP() XSTEP() XSTEP()
                            XSTEP() XSTEP() XSTEP() XSTEP()
                        }
                    }
                    asm volatile("s_waitcnt lgkmcnt(0)" ::: "memory");
                    SB();
                    __builtin_amdgcn_wave_barrier();
                    if (lane < CHUNK / 8) {
                        const float4 sb = sbnd[lane];
                        float u2 = sb.x, w2v = sb.y, v2 = sb.z;
                        float4* wdst = wlds[it & 1] + 2 * (lane * 8);
#pragma unroll
                        for (int k = 0; k < 8; ++k) {
                            float4 mv, xv;
                            mv.x = fmaf(-DT_C, u2, adt00);
                            mv.y = fmaf(-DT_C, w2v, adt10);
                            mv.z = fmaf(-DT_C, w2v, adt01);
                            mv.w = fmaf(-DT_C, v2, adt11);
                            xv = make_float4(u2, w2v, w2v, v2);
                            wdst[2 * k]     = mv;
                            wdst[2 * k + 1] = xv;
                            {
                                float u = u2, w = w2v, v = v2;
                                XSTEP()
                                u2 = u; w2v = w; v2 = v;
                            }
                        }
                    }
                }
                __syncthreads();
            }
#undef XSTEP
        } else {
            // generic path: full P, clips kept
#define RSTEP_G()                                                             \
            {                                                                 \
                const float xi00 = p00*c00 + p01*c01 + d00;                   \
                const float xi01 = p00*c10 + p01*c11 + d10;                   \
                const float xi10 = p10*c00 + p11*c01 + d01;                   \
                const float xi11 = p10*c10 + p11*c11 + d11;                   \
                const float g00 = a00*p00 + a01*p10 + p00*a00 + p01*a01 + d00 - (xi00*xi00 + xi01*xi01); \
                const float g01 = a00*p01 + a01*p11 + p00*a10 + p01*a11 + d01 - (xi00*xi10 + xi01*xi11); \
                const float g10 = a10*p00 + a11*p10 + p10*a00 + p11*a01 + d10 - (xi10*xi00 + xi11*xi01); \
                const float g11 = a10*p01 + a11*p11 + p10*a10 + p11*a11 + d11 - (xi10*xi10 + xi11*xi11); \
                p00 = clipf(p00 + g00 * DT_C, -1.f, 1.f);                     \
                p01 = clipf(p01 + g01 * DT_C, -1.f, 1.f);                     \
                p10 = clipf(p10 + g10 * DT_C, -1.f, 1.f);                     \
                p11 = clipf(p11 + g11 * DT_C, -1.f, 1.f);                     \
            }
            float p00 = 1.f, p01 = 0.f, p10 = 0.f, p11 = 1.f;
            for (int it = 0; it <= NCHUNK; ++it) {
                if (it < NCHUNK) {
                    if (lane == 0) {
                        for (int j = 0; j < CHUNK / 8; ++j) {
                            sbnd[j] = make_float4(p00, p01, p10, p11);
                            RSTEP_G() RSTEP_G() RSTEP_G() RSTEP_G()
                            RSTEP_G() RSTEP_G() RSTEP_G() RSTEP_G()
                        }
                    }
                    asm volatile("s_waitcnt lgkmcnt(0)" ::: "memory");
                    SB();
                    __builtin_amdgcn_wave_barrier();
                    if (lane < CHUNK / 8) {
                        const float4 sb = sbnd[lane];
                        float p00 = sb.x, p01 = sb.y, p10 = sb.z, p11 = sb.w;
                        float4* wdst = wlds[it & 1] + 2 * (lane * 8);
#pragma unroll
                        for (int k = 0; k < 8; ++k) {
                            const float xi00 = p00*c00 + p01*c01 + d00;
                            const float xi01 = p00*c10 + p01*c11 + d10;
                            const float xi10 = p10*c00 + p11*c01 + d01;
                            const float xi11 = p10*c10 + p11*c11 + d11;
                            const float m00 = a00 - (xi00*c00 + xi01*c10);
                            const float m01 = a01 - (xi00*c01 + xi01*c11);
                            const float m10 = a10 - (xi10*c00 + xi11*c10);
                            const float m11 = a11 - (xi10*c01 + xi11*c11);
                            float4 mv, xv;
                            mv.x = m00 * DT_C; mv.y = m10 * DT_C;
                            mv.z = m01 * DT_C; mv.w = m11 * DT_C;
                            xv = make_float4(xi00, xi10, xi01, xi11);
                            wdst[2 * k]     = mv;
                            wdst[2 * k + 1] = xv;
                            RSTEP_G()
                        }
                    }
                }
                __syncthreads();
            }
#undef RSTEP_G
        }
    } else {
        // ============= consumer wave: 2 rows/lane, packed math ===========
        const int lane = tid;
        const int b0 = blockIdx.x * 128 + lane;
        const int b1 = b0 + 64;
        const f2 CC0 = {Cm[0] * DT_C, Cm[2] * DT_C};   // C column 0 * dt
        const f2 CC1 = {Cm[1] * DT_C, Cm[3] * DT_C};   // C column 1 * dt
        const f4v* __restrict__ inTv = reinterpret_cast<const f4v*>(inT);
        f4v* __restrict__ outTv = reinterpret_cast<f4v*>(outT);

        f2 XA = {1.f, 0.f}, XB = {1.f, 0.f};
        // dy rings: 8-granule lookahead, both rows
        f4v dA0 = inTv[(size_t)0 * BROWS + b0], dB0 = inTv[(size_t)0 * BROWS + b1];
        f4v dA1 = inTv[(size_t)1 * BROWS + b0], dB1 = inTv[(size_t)1 * BROWS + b1];
        f4v dA2 = inTv[(size_t)2 * BROWS + b0], dB2 = inTv[(size_t)2 * BROWS + b1];
        f4v dA3 = inTv[(size_t)3 * BROWS + b0], dB3 = inTv[(size_t)3 * BROWS + b1];
        f4v dA4 = inTv[(size_t)4 * BROWS + b0], dB4 = inTv[(size_t)4 * BROWS + b1];
        f4v dA5 = inTv[(size_t)5 * BROWS + b0], dB5 = inTv[(size_t)5 * BROWS + b1];
        f4v dA6 = inTv[(size_t)6 * BROWS + b0], dB6 = inTv[(size_t)6 * BROWS + b1];
        f4v dA7 = inTv[(size_t)7 * BROWS + b0], dB7 = inTv[(size_t)7 * BROWS + b1];
        // W ring: 4 sets, SHARED between both rows
        f4v s0a, s0b, s0c, s0d, s1a, s1b, s1c, s1d;
        f4v t0a, t0b, t0c, t0d, t1a, t1b, t1c, t1d;

#define WLG(P, G)                                                             \
        {                                                                     \
            const int gg = (G) < G_CHUNK ? (G) : (G_CHUNK - 1);               \
            const f4v* wp = reinterpret_cast<const f4v*>(wbuf + 4 * gg);      \
            P##a = wp[0]; P##b = wp[1]; P##c = wp[2]; P##d = wp[3];           \
        }

        // one granule = 2 steps x 2 rows. P##a/c = Mdt, P##b/d = Xi.
#define GRAN2(P, DA, DB, OG)                                                  \
        {                                                                     \
            const f4v yA = DA, yB = DB;                                       \
            {                                                                 \
                const int nog = (OG) + 8;                                     \
                const int rg = nog < T4 ? nog : (T4 - 1);                     \
                DA = inTv[(size_t)rg * BROWS + b0];                           \
                DB = inTv[(size_t)rg * BROWS + b1];                           \
            }                                                                 \
            const f2 ma0 = P##a.xy, ma1 = P##a.zw;                            \
            const f2 xb0 = P##b.xy, xb1 = P##b.zw;                            \
            const f2 mc0 = P##c.xy, mc1 = P##c.zw;                            \
            const f2 xd0 = P##d.xy, xd1 = P##d.zw;                            \
            const f2 oA0 = pkfma(CC1, XA.yy, CC0 * XA.xx);                    \
            const f2 oB0 = pkfma(CC1, XB.yy, CC0 * XB.xx);                    \
            const f2 eA0 = pkfma(xb1, yA.yy, xb0 * yA.xx);                    \
            const f2 eB0 = pkfma(xb1, yB.yy, xb0 * yB.xx);                    \
            XA += pkclip(pkfma(ma0, XA.xx, pkfma(ma1, XA.yy, eA0)));          \
            XB += pkclip(pkfma(ma0, XB.xx, pkfma(ma1, XB.yy, eB0)));          \
            const f2 oA1 = pkfma(CC1, XA.yy, CC0 * XA.xx);                    \
            const f2 oB1 = pkfma(CC1, XB.yy, CC0 * XB.xx);                    \
            const f2 eA1 = pkfma(xd1, yA.ww, xd0 * yA.zz);                    \
            const f2 eB1 = pkfma(xd1, yB.ww, xd0 * yB.zz);                    \
            XA += pkclip(pkfma(mc0, XA.xx, pkfma(mc1, XA.yy, eA1)));          \
            XB += pkclip(pkfma(mc0, XB.xx, pkfma(mc1, XB.yy, eB1)));          \
            f4v o4A, o4B;                                                     \
            o4A.xy = oA0; o4A.zw = oA1;                                       \
            o4B.xy = oB0; o4B.zw = oB1;                                       \
            outTv[(size_t)(OG) * BROWS + b0] = o4A;                           \
            outTv[(size_t)(OG) * BROWS + b1] = o4B;                           \
        }

        for (int it = 0; it <= NCHUNK; ++it) {
            if (it > 0) {
                const int cc = it - 1;
                const float4* wbuf = wlds[cc & 1];
                const int ogc = cc * G_CHUNK;
                WLG(s0, 0) WLG(s1, 1) WLG(t0, 2) WLG(t1, 3)
                SB();
                for (int q = 0; q < G_CHUNK / 8; ++q) {
                    const int g = 8 * q;
                    const int og = ogc + g;
                    GRAN2(s0, dA0, dB0, og + 0) GRAN2(s1, dA1, dB1, og + 1) SB();
                    WLG(s0, g + 4) WLG(s1, g + 5) SB();
                    GRAN2(t0, dA2, dB2, og + 2) GRAN2(t1, dA3, dB3, og + 3) SB();
                    WLG(t0, g + 6) WLG(t1, g + 7) SB();
                    GRAN2(s0, dA4, dB4, og + 4) GRAN2(s1, dA5, dB5, og + 5) SB();
                    WLG(s0, g + 8) WLG(s1, g + 9) SB();
                    GRAN2(t0, dA6, dB6, og + 6) GRAN2(t1, dA7, dB7, og + 7) SB();
                    WLG(t0, g + 10) WLG(t1, g + 11) SB();
                }
            }
            __syncthreads();
        }
#undef GRAN2
#undef WLG
    }
}

// ---------------- fallback: verified monolithic kernel --------------------
__global__ __launch_bounds__(64) void grnn_mono(
    const float* __restrict__ inp, const float* __restrict__ Am,
    const float* __restrict__ Cm, const float* __restrict__ Dm,
    float* __restrict__ out, int B)
{
    const int b = blockIdx.x * blockDim.x + threadIdx.x;
    if (b >= B) return;
    const float a00 = Am[0], a01 = Am[1], a10 = Am[2], a11 = Am[3];
    const float c00 = Cm[0], c01 = Cm[1], c10 = Cm[2], c11 = Cm[3];
    const float d00 = Dm[0], d01 = Dm[1], d10 = Dm[2], d11 = Dm[3];
    float x0 = 1.0f, x1 = 0.0f;
    float p00 = 1.0f, p01 = 0.0f, p10 = 0.0f, p11 = 1.0f;
    const float2* __restrict__ in2 = reinterpret_cast<const float2*>(inp) + (size_t)b * T_LEN;
    float2* __restrict__ out2 = reinterpret_cast<float2*>(out) + (size_t)b * T_LEN;
#pragma unroll 4
    for (int t = 0; t < T_LEN; ++t) {
        float2 o;
        o.x = (c00 * x0 + c01 * x1) * DT_C;
        o.y = (c10 * x0 + c11 * x1) * DT_C;
        out2[t] = o;
        const float xi00 = p00 * c00 + p01 * c01 + d00;
        const float xi01 = p00 * c10 + p01 * c11 + d10;
        const float xi10 = p10 * c00 + p11 * c01 + d01;
        const float xi11 = p10 * c10 + p11 * c11 + d11;
        const float m00 = a00 - (xi00 * c00 + xi01 * c10);
        const float m01 = a01 - (xi00 * c01 + xi01 * c11);
        const float m10 = a10 - (xi10 * c00 + xi11 * c10);
        const float m11 = a11 - (xi10 * c01 + xi11 * c11);
        const float2 dy = in2[t];
        float dx0 = (m00 * x0 + m01 * x1) * DT_C + xi00 * dy.x + xi01 * dy.y;
        float dx1 = (m10 * x0 + m11 * x1) * DT_C + xi10 * dy.x + xi11 * dy.y;
        x0 += clipf(dx0, -MAXU, MAXU);
        x1 += clipf(dx1, -MAXU, MAXU);
        const float g00 = a00*p00 + a01*p10 + p00*a00 + p01*a01 + d00 - (xi00*xi00 + xi01*xi01);
        const float g01 = a00*p01 + a01*p11 + p00*a10 + p01*a11 + d01 - (xi00*xi10 + xi01*xi11);
        const float g10 = a10*p00 + a11*p10 + p10*a00 + p11*a01 + d10 - (xi10*xi00 + xi11*xi01);
        const float g11 = a10*p01 + a11*p11 + p10*a10 + p11*a11 + d11 - (xi10*xi10 + xi11*xi11);
        p00 = clipf(p00 + g00 * DT_C, -1.0f, 1.0f);
        p01 = clipf(p01 + g01 * DT_C, -1.0f, 1.0f);
        p10 = clipf(p10 + g10 * DT_C, -1.0f, 1.0f);
        p11 = clipf(p11 + g11 * DT_C, -1.0f, 1.0f);
    }
}

extern "C" void kernel_launch(void* const* d_in, const int* in_sizes, int n_in,
                              void* d_out, int out_size, void* d_ws, size_t ws_size,
                              hipStream_t stream) {
    const float* inp = (const float*)d_in[0];
    const float* Am  = (const float*)d_in[1];
    const float* Cm  = (const float*)d_in[2];
    const float* Dm  = (const float*)d_in[3];
    float* out = (float*)d_out;
    const int B = in_sizes[0] / (T_LEN * 2);  // 512

    float4* inT  = (float4*)d_ws;                       // [T4][BROWS]
    float4* outT = inT + (size_t)T4 * BROWS;
    const size_t need_ws = (size_t)2 * T4 * BROWS * sizeof(float4);  // 64 MiB

    if (B == BROWS && d_ws != nullptr && ws_size >= need_ws) {
        // 1) transpose input [B][T4] -> [T4][B]
        hipLaunchKernelGGL(transpose_f4, dim3(T4 / 32, BROWS / 32), dim3(256),
                           0, stream,
                           reinterpret_cast<const float4*>(inp), inT,
                           BROWS, T4);
        // 2) fused producer/consumer scan, 2 rows/lane, packed math
        hipLaunchKernelGGL(grnn_fused3, dim3(BROWS / 128), dim3(128), 0,
                           stream, inT, Am, Cm, Dm, outT);
        // 3) transpose output [T4][B] -> [B][T4]
        hipLaunchKernelGGL(transpose_f4, dim3(BROWS / 32, T4 / 32), dim3(256),
                           0, stream,
                           outT, reinterpret_cast<float4*>(out), T4, BROWS);
    } else {
        hipLaunchKernelGGL(grnn_mono, dim3((B + 63) / 64), dim3(64), 0, stream,
                           inp, Am, Cm, Dm, out, B);
    }
}